// Round 8
// baseline (4215.755 us; speedup 1.0000x reference)
//
#include <hip/hip_runtime.h>
#include <hip/hip_fp16.h>
#include <hip/hip_bf16.h>

#define TSTEPS 1019
#define BATCH 8
#define CIN 4
#define LEN 524288
#define COUT 512
#define HID 512
#define KERN 3072
#define CSTRIDE 512
#define KTOT (CIN * KERN)          // 12288
#define MROWS (TSTEPS * BATCH)     // 8152

typedef _Float16 half2_v __attribute__((ext_vector_type(2)));
typedef __attribute__((ext_vector_type(8))) short bf16x8;
typedef __attribute__((ext_vector_type(4))) float f32x4;

#if defined(__has_builtin)
#if __has_builtin(__builtin_amdgcn_fdot2)
#define HAVE_FDOT2 1
#endif
#endif

__device__ __forceinline__ float dot2f(__half2 a, __half2 b, float c) {
#ifdef HAVE_FDOT2
    return __builtin_amdgcn_fdot2(__builtin_bit_cast(half2_v, a),
                                  __builtin_bit_cast(half2_v, b), c, false);
#else
    float2 af = __half22float2(a), bf = __half22float2(b);
    return fmaf(af.y, bf.y, fmaf(af.x, bf.x, c));
#endif
}

struct __align__(16) H2x4 { __half2 x, y, z, w; };

__device__ __forceinline__ short bfc(float x) {
    return (short)__builtin_bit_cast(unsigned short, __float2bfloat16(x));
}

__device__ __forceinline__ void load_lds16(const unsigned short* g, unsigned short* l) {
    __builtin_amdgcn_global_load_lds(
        (const __attribute__((address_space(1))) void*)g,
        (__attribute__((address_space(3))) void*)l, 16, 0, 0);
}

// L1-bypassing load (sc0): served from the local XCD L2 if the line is there.
__device__ __forceinline__ unsigned long long load_fast(
        const unsigned long long* p) {
    unsigned long long v;
    asm volatile("global_load_dwordx2 %0, %1, off sc0\n\t"
                 "s_waitcnt vmcnt(0)"
                 : "=v"(v) : "v"(p) : "memory");
    return v;
}

// ---------------------------------------------------------------------------
// fp32 -> bf16 convert (unchanged)
// ---------------------------------------------------------------------------
__global__ __launch_bounds__(256) void f2bf_k(
        const float* __restrict__ a, unsigned short* __restrict__ o, int n4) {
    int i = blockIdx.x * blockDim.x + threadIdx.x;
    int stride = gridDim.x * blockDim.x;
    for (; i < n4; i += stride) {
        float4 f = reinterpret_cast<const float4*>(a)[i];
        ushort4 u;
        u.x = (unsigned short)bfc(f.x); u.y = (unsigned short)bfc(f.y);
        u.z = (unsigned short)bfc(f.z); u.w = (unsigned short)bfc(f.w);
        reinterpret_cast<ushort4*>(o)[i] = u;
    }
}

// ---------------------------------------------------------------------------
// Conv1d implicit GEMM on MFMA (unchanged from round 4)
// ---------------------------------------------------------------------------
__global__ __launch_bounds__(256, 2) void conv_mfma_k(
        const float* __restrict__ in, const unsigned short* __restrict__ wb,
        const float* __restrict__ bias, unsigned short* __restrict__ out) {
    __shared__ unsigned short At[2][128 * 64];
    __shared__ unsigned short Bt[2][128 * 64];
    const int m0 = blockIdx.y * 128;
    const int n0 = blockIdx.x * 128;
    const int tid = threadIdx.x;
    const int w = tid >> 6, l = tid & 63;
    const int wm = w >> 1, wn = w & 1;
    const int fr = l & 15, fq = l >> 4;

    const int ra = tid >> 1, hh = tid & 1;
    int mA = m0 + ra; if (mA > MROWS - 1) mA = MROWS - 1;
    const int tA = mA >> 3, bA = mA & 7;

    f32x4 acc[4][4] = {};
    const int NT = KTOT / 64;

    {
        const float* src = in + (size_t)(bA * CIN + 0) * LEN
                              + (size_t)tA * CSTRIDE + 0 + hh * 32;
        #pragma unroll
        for (int cc = 0; cc < 4; ++cc) {
            float4 f0 = reinterpret_cast<const float4*>(src)[cc * 2];
            float4 f1 = reinterpret_cast<const float4*>(src)[cc * 2 + 1];
            bf16x8 v;
            v[0] = bfc(f0.x); v[1] = bfc(f0.y); v[2] = bfc(f0.z); v[3] = bfc(f0.w);
            v[4] = bfc(f1.x); v[5] = bfc(f1.y); v[6] = bfc(f1.z); v[7] = bfc(f1.w);
            const int c = hh * 4 + cc, s = c ^ (ra & 7);
            *reinterpret_cast<bf16x8*>(&At[0][ra * 64 + s * 8]) = v;
        }
        #pragma unroll
        for (int i = 0; i < 4; ++i) {
            const int rb = w * 32 + i * 8 + (l >> 3);
            const int s = l & 7, c = s ^ (rb & 7);
            load_lds16(wb + (size_t)(n0 + rb) * KTOT + 0 + c * 8,
                       &Bt[0][(w * 32 + i * 8) * 64]);
        }
    }
    __syncthreads();

    int cur = 0;
    for (int t = 0; t < NT; ++t) {
        const int nxt = cur ^ 1;
        float4 fA[8];
        const bool more = (t + 1 < NT);
        if (more) {
            const int k0 = (t + 1) * 64;
            const int ci = k0 / KERN, kr = k0 - ci * KERN;
            const float* src = in + (size_t)(bA * CIN + ci) * LEN
                                  + (size_t)tA * CSTRIDE + kr + hh * 32;
            #pragma unroll
            for (int v = 0; v < 8; ++v)
                fA[v] = reinterpret_cast<const float4*>(src)[v];
            #pragma unroll
            for (int i = 0; i < 4; ++i) {
                const int rb = w * 32 + i * 8 + (l >> 3);
                const int s = l & 7, c = s ^ (rb & 7);
                load_lds16(wb + (size_t)(n0 + rb) * KTOT + k0 + c * 8,
                           &Bt[nxt][(w * 32 + i * 8) * 64]);
            }
        }
        #pragma unroll
        for (int ks = 0; ks < 2; ++ks) {
            bf16x8 af[4], bfg[4];
            #pragma unroll
            for (int mf = 0; mf < 4; ++mf) {
                const int rA = wm * 64 + mf * 16 + fr;
                const int cw = ks * 4 + fq, s = cw ^ (rA & 7);
                af[mf] = *reinterpret_cast<const bf16x8*>(&At[cur][rA * 64 + s * 8]);
            }
            #pragma unroll
            for (int nf = 0; nf < 4; ++nf) {
                const int rB = wn * 64 + nf * 16 + fr;
                const int cw = ks * 4 + fq, s = cw ^ (rB & 7);
                bfg[nf] = *reinterpret_cast<const bf16x8*>(&Bt[cur][rB * 64 + s * 8]);
            }
            #pragma unroll
            for (int mf = 0; mf < 4; ++mf)
                #pragma unroll
                for (int nf = 0; nf < 4; ++nf)
                    acc[mf][nf] = __builtin_amdgcn_mfma_f32_16x16x32_bf16(
                        af[mf], bfg[nf], acc[mf][nf], 0, 0, 0);
        }
        if (more) {
            #pragma unroll
            for (int cc = 0; cc < 4; ++cc) {
                float4 f0 = fA[cc * 2], f1 = fA[cc * 2 + 1];
                bf16x8 v;
                v[0] = bfc(f0.x); v[1] = bfc(f0.y); v[2] = bfc(f0.z); v[3] = bfc(f0.w);
                v[4] = bfc(f1.x); v[5] = bfc(f1.y); v[6] = bfc(f1.z); v[7] = bfc(f1.w);
                const int c = hh * 4 + cc, s = c ^ (ra & 7);
                *reinterpret_cast<bf16x8*>(&At[nxt][ra * 64 + s * 8]) = v;
            }
        }
        __syncthreads();
        cur = nxt;
    }

    #pragma unroll
    for (int nf = 0; nf < 4; ++nf) {
        const int n = n0 + wn * 64 + nf * 16 + fr;
        const float bv = bias[n];
        #pragma unroll
        for (int mf = 0; mf < 4; ++mf) {
            #pragma unroll
            for (int i = 0; i < 4; ++i) {
                const int m = m0 + wm * 64 + mf * 16 + fq * 4 + i;
                if (m < MROWS)
                    out[(size_t)m * COUT + n] =
                        (unsigned short)bfc(acc[mf][nf][i] + bv);
            }
        }
    }
}

// ---------------------------------------------------------------------------
// gi projection MFMA (unchanged from round 4)
// ---------------------------------------------------------------------------
__global__ __launch_bounds__(256, 2) void proj_mfma_k(
        const unsigned short* __restrict__ A, const unsigned short* __restrict__ wb,
        const float* __restrict__ bias, float* __restrict__ out) {
    __shared__ unsigned short At[2][128 * 64];
    __shared__ unsigned short Bt[2][128 * 64];
    const int m0 = blockIdx.y * 128;
    const int n0 = blockIdx.x * 128;
    const int tid = threadIdx.x;
    const int w = tid >> 6, l = tid & 63;
    const int wm = w >> 1, wn = w & 1;
    const int fr = l & 15, fq = l >> 4;

    f32x4 acc[4][4] = {};
    const int NT = COUT / 64;

    auto stage = [&](int buf, int k0) {
        #pragma unroll
        for (int i = 0; i < 4; ++i) {
            const int r = w * 32 + i * 8 + (l >> 3);
            const int s = l & 7, c = s ^ (r & 7);
            int mA = m0 + r; if (mA > MROWS - 1) mA = MROWS - 1;
            load_lds16(A + (size_t)mA * COUT + k0 + c * 8,
                       &At[buf][(w * 32 + i * 8) * 64]);
            load_lds16(wb + (size_t)(n0 + r) * COUT + k0 + c * 8,
                       &Bt[buf][(w * 32 + i * 8) * 64]);
        }
    };

    stage(0, 0);
    __syncthreads();
    int cur = 0;
    for (int t = 0; t < NT; ++t) {
        const int nxt = cur ^ 1;
        if (t + 1 < NT) stage(nxt, (t + 1) * 64);
        #pragma unroll
        for (int ks = 0; ks < 2; ++ks) {
            bf16x8 af[4], bfg[4];
            #pragma unroll
            for (int mf = 0; mf < 4; ++mf) {
                const int rA = wm * 64 + mf * 16 + fr;
                const int cw = ks * 4 + fq, s = cw ^ (rA & 7);
                af[mf] = *reinterpret_cast<const bf16x8*>(&At[cur][rA * 64 + s * 8]);
            }
            #pragma unroll
            for (int nf = 0; nf < 4; ++nf) {
                const int rB = wn * 64 + nf * 16 + fr;
                const int cw = ks * 4 + fq, s = cw ^ (rB & 7);
                bfg[nf] = *reinterpret_cast<const bf16x8*>(&Bt[cur][rB * 64 + s * 8]);
            }
            #pragma unroll
            for (int mf = 0; mf < 4; ++mf)
                #pragma unroll
                for (int nf = 0; nf < 4; ++nf)
                    acc[mf][nf] = __builtin_amdgcn_mfma_f32_16x16x32_bf16(
                        af[mf], bfg[nf], acc[mf][nf], 0, 0, 0);
        }
        __syncthreads();
        cur = nxt;
    }

    #pragma unroll
    for (int nf = 0; nf < 4; ++nf) {
        const int n = n0 + wn * 64 + nf * 16 + fr;
        const float bv = bias[n];
        #pragma unroll
        for (int mf = 0; mf < 4; ++mf) {
            #pragma unroll
            for (int i = 0; i < 4; ++i) {
                const int m = m0 + wm * 64 + mf * 16 + fq * 4 + i;
                if (m < MROWS)
                    out[(size_t)m * 1536 + n] = acc[mf][nf][i] + bv;
            }
        }
    }
}

// ---------------------------------------------------------------------------
// GRU scan, round 8. 8 teams x 8 slice-blocks (team = bid&7: same XCD under
// round-robin dispatch — perf heuristic only). Block owns 64 rows; wave owns
// 8 rows x full K: lane=(r=l&7, c=l>>3), 96 half2 weights/thread (VGPR-
// resident via __launch_bounds__(512,2)). k-reduce = 3 shfl_xor — no p_lds,
// ONE barrier/step. Gates redundant per-lane (no divergence). Exchange:
// parity-double-buffered {epoch:32|2xfp16:32} words, written twice (plain
// store -> producer L2; relaxed agent store -> MALL, authoritative).
// Consumer: 24 sc0 spins on the L2 copy (same-XCD fast path), then agent-
// scope poll forever. Deadlock-free by the round-3 parity proof on the slow
// path; fast path inherits the same non-overwrite guarantee (producer writes
// epoch e+3 to a parity only after polling e+2, which requires all peers
// consumed e+1 from that parity).
// ---------------------------------------------------------------------------
__global__ __launch_bounds__(512, 2) void gru_scan_k(
        const float* __restrict__ gi, const float* __restrict__ w_hh,
        const float* __restrict__ b_hh, const float* __restrict__ hidden,
        float* __restrict__ out, unsigned long long* __restrict__ h_ex) {
    const int bid = blockIdx.x;
    const int b   = bid & 7;           // team/batch -> XCD (heuristic)
    const int isl = bid >> 3;          // slice 0..7
    const int tid = threadIdx.x;
    const int wv  = tid >> 6;          // wave 0..7
    const int l   = tid & 63;
    const int r   = l & 7;             // row within wave's 8
    const int c   = l >> 3;            // 64-k chunk 0..7
    const int j   = isl * 64 + wv * 8 + r;   // owned h row

    __shared__ __align__(16) __half2 hh2[2][288];   // 8 groups x (32+4 pad)

    unsigned long long* hfast = h_ex;               // [2][8][256] L2 copy
    unsigned long long* hslow = h_ex + 4096;        // [2][8][256] MALL copy

    // weights: 3 gates x 64 k (chunk c) of row j -> 96 half2 VGPRs
    __half2 wreg[3][32];
    #pragma unroll
    for (int m = 0; m < 3; ++m) {
        const float* wp = w_hh + (size_t)(j + m * 512) * HID + c * 64;
        #pragma unroll
        for (int kk = 0; kk < 16; ++kk) {
            float4 v = reinterpret_cast<const float4*>(wp)[kk];
            wreg[m][2 * kk]     = __halves2half2(__float2half_rn(v.x), __float2half_rn(v.y));
            wreg[m][2 * kk + 1] = __halves2half2(__float2half_rn(v.z), __float2half_rn(v.w));
        }
    }

    const float bhr = b_hh[j], bhz = b_hh[j + 512], bhn = b_hh[j + 1024];
    float hprev = hidden[b * HID + j];
    float gir = gi[(size_t)b * 1536 + j];
    float giz = gi[(size_t)b * 1536 + j + 512];
    float gin = gi[(size_t)b * 1536 + j + 1024];

    if (tid < 256)
        hh2[0][(tid >> 5) * 36 + (tid & 31)] =
            __halves2half2(__float2half(hidden[b * HID + 2 * tid]),
                           __float2half(hidden[b * HID + 2 * tid + 1]));
    __syncthreads();

    for (int t = 0; t < TSTEPS; ++t) {
        const bool more = (t + 1 < TSTEPS);
        const int pn = (t + 1) & 1;    // parity of the buffer being produced
        // --- matvec over own 64-k chunk: 96 dot2, conflict-free broadcasts ---
        const H2x4* hv4 = reinterpret_cast<const H2x4*>(&hh2[t & 1][c * 36]);
        float a0 = 0, a1 = 0, a2 = 0, c0 = 0, c1 = 0, c2 = 0;
        #pragma unroll
        for (int kk = 0; kk < 8; ++kk) {
            H2x4 h4 = hv4[kk];
            a0 = dot2f(wreg[0][4 * kk + 0], h4.x, a0);
            a1 = dot2f(wreg[1][4 * kk + 0], h4.x, a1);
            a2 = dot2f(wreg[2][4 * kk + 0], h4.x, a2);
            c0 = dot2f(wreg[0][4 * kk + 1], h4.y, c0);
            c1 = dot2f(wreg[1][4 * kk + 1], h4.y, c1);
            c2 = dot2f(wreg[2][4 * kk + 1], h4.y, c2);
            a0 = dot2f(wreg[0][4 * kk + 2], h4.z, a0);
            a1 = dot2f(wreg[1][4 * kk + 2], h4.z, a1);
            a2 = dot2f(wreg[2][4 * kk + 2], h4.z, a2);
            c0 = dot2f(wreg[0][4 * kk + 3], h4.w, c0);
            c1 = dot2f(wreg[1][4 * kk + 3], h4.w, c1);
            c2 = dot2f(wreg[2][4 * kk + 3], h4.w, c2);
        }
        // --- wave-local k-reduce across the 8 c-lanes ---
        float ghr = a0 + c0, ghz = a1 + c1, ghn = a2 + c2;
        ghr += __shfl_xor(ghr, 8); ghr += __shfl_xor(ghr, 16); ghr += __shfl_xor(ghr, 32);
        ghz += __shfl_xor(ghz, 8); ghz += __shfl_xor(ghz, 16); ghz += __shfl_xor(ghz, 32);
        ghn += __shfl_xor(ghn, 8); ghn += __shfl_xor(ghn, 16); ghn += __shfl_xor(ghn, 32);
        // --- gates (redundant across c; no divergence) ---
        const float rr = 1.f / (1.f + __expf(-(gir + ghr + bhr)));
        const float zz = 1.f / (1.f + __expf(-(giz + ghz + bhz)));
        const float nx = gin + rr * (ghn + bhn);
        const float nn = 1.f - 2.f / (__expf(2.f * nx) + 1.f);   // tanh
        const float hnew = (1.f - zz) * nn + zz * hprev;
        hprev = hnew;
        const float hother = __shfl_xor(hnew, 1);   // row pair partner

        if (c == 0) {
            out[(size_t)(t * BATCH + b) * HID + j] = hnew;
            if (more && !(r & 1)) {
                const __half2 h2 = __halves2half2(__float2half(hnew),
                                                  __float2half(hother));
                const unsigned long long v =
                    ((unsigned long long)(unsigned)(t + 1) << 32) |
                    (unsigned long long)__builtin_bit_cast(unsigned, h2);
                const int w0 = (j >> 1);            // word 0..255 (own slice)
                const size_t idx = (size_t)(pn * BATCH + b) * 256 + w0;
                hfast[idx] = v;                                   // L2 copy
                __hip_atomic_store(&hslow[idx], v, __ATOMIC_RELAXED,
                                   __HIP_MEMORY_SCOPE_AGENT);     // authoritative
                hh2[pn][(w0 >> 5) * 36 + (w0 & 31)] = h2;         // own slice
            }
        }
        if (!more) break;

        // prefetch gi[t+1] (hides under the poll)
        {
            const float* gp = gi + (size_t)((t + 1) * BATCH + b) * 1536 + j;
            gir = gp[0]; giz = gp[512]; gin = gp[1024];
        }

        // --- poll 224 remote words: sc0 fast path, then agent-scope forever ---
        if (tid < 224) {
            const int w0 = tid + ((tid >= isl * 32) ? 32 : 0);
            const size_t idx = (size_t)(pn * BATCH + b) * 256 + w0;
            unsigned long long v; bool got = false;
            #pragma unroll 1
            for (int it = 0; it < 24; ++it) {
                v = load_fast(&hfast[idx]);
                if ((unsigned)(v >> 32) == (unsigned)(t + 1)) { got = true; break; }
            }
            if (!got) {
                do {
                    v = __hip_atomic_load(&hslow[idx], __ATOMIC_RELAXED,
                                          __HIP_MEMORY_SCOPE_AGENT);
                } while ((unsigned)(v >> 32) != (unsigned)(t + 1));
            }
            hh2[pn][(w0 >> 5) * 36 + (w0 & 31)] =
                __builtin_bit_cast(__half2, (unsigned)(v & 0xffffffffu));
        }
        __syncthreads();   // writes to parity pn done before next matvec reads
    }
    if (c == 0)
        out[(size_t)TSTEPS * BATCH * HID + b * HID + j] = hprev;
}

extern "C" void kernel_launch(void* const* d_in, const int* in_sizes, int n_in,
                              void* d_out, int out_size, void* d_ws, size_t ws_size,
                              hipStream_t stream) {
    (void)in_sizes; (void)n_in; (void)out_size; (void)ws_size;
    const float* input  = (const float*)d_in[0];
    const float* hidden = (const float*)d_in[1];
    const float* conv_w = (const float*)d_in[2];
    const float* conv_b = (const float*)d_in[3];
    const float* w_ih   = (const float*)d_in[4];
    const float* w_hh   = (const float*)d_in[5];
    const float* b_ih   = (const float*)d_in[6];
    const float* b_hh   = (const float*)d_in[7];
    float* out = (float*)d_out;

    char* ws = (char*)d_ws;
    float*          gi       = (float*)ws;                          // 50,085,888 B
    unsigned short* conv_out = (unsigned short*)(ws + 50085888);    //  8,347,648 B
    unsigned short* w_bf     = (unsigned short*)(ws + 58433536);    // 12,582,912 B
    unsigned short* wih_bf   = (unsigned short*)(ws + 71016448);    //  1,572,864 B
    unsigned long long* h_ex = (unsigned long long*)(ws + 72589312);//     65,536 B

    f2bf_k<<<2048, 256, 0, stream>>>(conv_w, w_bf, KTOT * COUT / 4);
    f2bf_k<<<768, 256, 0, stream>>>(w_ih, wih_bf, 1536 * COUT / 4);

    dim3 cgrid(4, 64);
    conv_mfma_k<<<cgrid, 256, 0, stream>>>(input, w_bf, conv_b, conv_out);

    dim3 pgrid(12, 64);
    proj_mfma_k<<<pgrid, 256, 0, stream>>>(conv_out, wih_bf, b_ih, gi);

    // reset exchange epochs each launch (replays don't re-poison d_ws)
    hipMemsetAsync(h_ex, 0, 65536, stream);

    gru_scan_k<<<64, 512, 0, stream>>>(gi, w_hh, b_hh, hidden, out, h_ex);
}

// Round 9
// 2129.123 us; speedup vs baseline: 1.9800x; 1.9800x over previous
//
#include <hip/hip_runtime.h>
#include <hip/hip_fp16.h>
#include <hip/hip_bf16.h>

#define TSTEPS 1019
#define BATCH 8
#define CIN 4
#define LEN 524288
#define COUT 512
#define HID 512
#define KERN 3072
#define CSTRIDE 512
#define KTOT (CIN * KERN)          // 12288
#define MROWS (TSTEPS * BATCH)     // 8152

typedef _Float16 half2_v __attribute__((ext_vector_type(2)));
typedef __attribute__((ext_vector_type(8))) short bf16x8;
typedef __attribute__((ext_vector_type(4))) float f32x4;

#if defined(__has_builtin)
#if __has_builtin(__builtin_amdgcn_fdot2)
#define HAVE_FDOT2 1
#endif
#endif

__device__ __forceinline__ float dot2f(__half2 a, __half2 b, float c) {
#ifdef HAVE_FDOT2
    return __builtin_amdgcn_fdot2(__builtin_bit_cast(half2_v, a),
                                  __builtin_bit_cast(half2_v, b), c, false);
#else
    float2 af = __half22float2(a), bf = __half22float2(b);
    return fmaf(af.y, bf.y, fmaf(af.x, bf.x, c));
#endif
}

struct __align__(16) H2x4 { __half2 x, y, z, w; };

__device__ __forceinline__ short bfc(float x) {
    return (short)__builtin_bit_cast(unsigned short, __float2bfloat16(x));
}

__device__ __forceinline__ void load_lds16(const unsigned short* g, unsigned short* l) {
    __builtin_amdgcn_global_load_lds(
        (const __attribute__((address_space(1))) void*)g,
        (__attribute__((address_space(3))) void*)l, 16, 0, 0);
}

// ---------------------------------------------------------------------------
// fp32 -> bf16 convert (unchanged)
// ---------------------------------------------------------------------------
__global__ __launch_bounds__(256) void f2bf_k(
        const float* __restrict__ a, unsigned short* __restrict__ o, int n4) {
    int i = blockIdx.x * blockDim.x + threadIdx.x;
    int stride = gridDim.x * blockDim.x;
    for (; i < n4; i += stride) {
        float4 f = reinterpret_cast<const float4*>(a)[i];
        ushort4 u;
        u.x = (unsigned short)bfc(f.x); u.y = (unsigned short)bfc(f.y);
        u.z = (unsigned short)bfc(f.z); u.w = (unsigned short)bfc(f.w);
        reinterpret_cast<ushort4*>(o)[i] = u;
    }
}

// ---------------------------------------------------------------------------
// Conv1d implicit GEMM on MFMA (unchanged from round 4)
// ---------------------------------------------------------------------------
__global__ __launch_bounds__(256, 2) void conv_mfma_k(
        const float* __restrict__ in, const unsigned short* __restrict__ wb,
        const float* __restrict__ bias, unsigned short* __restrict__ out) {
    __shared__ unsigned short At[2][128 * 64];
    __shared__ unsigned short Bt[2][128 * 64];
    const int m0 = blockIdx.y * 128;
    const int n0 = blockIdx.x * 128;
    const int tid = threadIdx.x;
    const int w = tid >> 6, l = tid & 63;
    const int wm = w >> 1, wn = w & 1;
    const int fr = l & 15, fq = l >> 4;

    const int ra = tid >> 1, hh = tid & 1;
    int mA = m0 + ra; if (mA > MROWS - 1) mA = MROWS - 1;
    const int tA = mA >> 3, bA = mA & 7;

    f32x4 acc[4][4] = {};
    const int NT = KTOT / 64;

    {
        const float* src = in + (size_t)(bA * CIN + 0) * LEN
                              + (size_t)tA * CSTRIDE + 0 + hh * 32;
        #pragma unroll
        for (int cc = 0; cc < 4; ++cc) {
            float4 f0 = reinterpret_cast<const float4*>(src)[cc * 2];
            float4 f1 = reinterpret_cast<const float4*>(src)[cc * 2 + 1];
            bf16x8 v;
            v[0] = bfc(f0.x); v[1] = bfc(f0.y); v[2] = bfc(f0.z); v[3] = bfc(f0.w);
            v[4] = bfc(f1.x); v[5] = bfc(f1.y); v[6] = bfc(f1.z); v[7] = bfc(f1.w);
            const int c = hh * 4 + cc, s = c ^ (ra & 7);
            *reinterpret_cast<bf16x8*>(&At[0][ra * 64 + s * 8]) = v;
        }
        #pragma unroll
        for (int i = 0; i < 4; ++i) {
            const int rb = w * 32 + i * 8 + (l >> 3);
            const int s = l & 7, c = s ^ (rb & 7);
            load_lds16(wb + (size_t)(n0 + rb) * KTOT + 0 + c * 8,
                       &Bt[0][(w * 32 + i * 8) * 64]);
        }
    }
    __syncthreads();

    int cur = 0;
    for (int t = 0; t < NT; ++t) {
        const int nxt = cur ^ 1;
        float4 fA[8];
        const bool more = (t + 1 < NT);
        if (more) {
            const int k0 = (t + 1) * 64;
            const int ci = k0 / KERN, kr = k0 - ci * KERN;
            const float* src = in + (size_t)(bA * CIN + ci) * LEN
                                  + (size_t)tA * CSTRIDE + kr + hh * 32;
            #pragma unroll
            for (int v = 0; v < 8; ++v)
                fA[v] = reinterpret_cast<const float4*>(src)[v];
            #pragma unroll
            for (int i = 0; i < 4; ++i) {
                const int rb = w * 32 + i * 8 + (l >> 3);
                const int s = l & 7, c = s ^ (rb & 7);
                load_lds16(wb + (size_t)(n0 + rb) * KTOT + k0 + c * 8,
                           &Bt[nxt][(w * 32 + i * 8) * 64]);
            }
        }
        #pragma unroll
        for (int ks = 0; ks < 2; ++ks) {
            bf16x8 af[4], bfg[4];
            #pragma unroll
            for (int mf = 0; mf < 4; ++mf) {
                const int rA = wm * 64 + mf * 16 + fr;
                const int cw = ks * 4 + fq, s = cw ^ (rA & 7);
                af[mf] = *reinterpret_cast<const bf16x8*>(&At[cur][rA * 64 + s * 8]);
            }
            #pragma unroll
            for (int nf = 0; nf < 4; ++nf) {
                const int rB = wn * 64 + nf * 16 + fr;
                const int cw = ks * 4 + fq, s = cw ^ (rB & 7);
                bfg[nf] = *reinterpret_cast<const bf16x8*>(&Bt[cur][rB * 64 + s * 8]);
            }
            #pragma unroll
            for (int mf = 0; mf < 4; ++mf)
                #pragma unroll
                for (int nf = 0; nf < 4; ++nf)
                    acc[mf][nf] = __builtin_amdgcn_mfma_f32_16x16x32_bf16(
                        af[mf], bfg[nf], acc[mf][nf], 0, 0, 0);
        }
        if (more) {
            #pragma unroll
            for (int cc = 0; cc < 4; ++cc) {
                float4 f0 = fA[cc * 2], f1 = fA[cc * 2 + 1];
                bf16x8 v;
                v[0] = bfc(f0.x); v[1] = bfc(f0.y); v[2] = bfc(f0.z); v[3] = bfc(f0.w);
                v[4] = bfc(f1.x); v[5] = bfc(f1.y); v[6] = bfc(f1.z); v[7] = bfc(f1.w);
                const int c = hh * 4 + cc, s = c ^ (ra & 7);
                *reinterpret_cast<bf16x8*>(&At[nxt][ra * 64 + s * 8]) = v;
            }
        }
        __syncthreads();
        cur = nxt;
    }

    #pragma unroll
    for (int nf = 0; nf < 4; ++nf) {
        const int n = n0 + wn * 64 + nf * 16 + fr;
        const float bv = bias[n];
        #pragma unroll
        for (int mf = 0; mf < 4; ++mf) {
            #pragma unroll
            for (int i = 0; i < 4; ++i) {
                const int m = m0 + wm * 64 + mf * 16 + fq * 4 + i;
                if (m < MROWS)
                    out[(size_t)m * COUT + n] =
                        (unsigned short)bfc(acc[mf][nf][i] + bv);
            }
        }
    }
}

// ---------------------------------------------------------------------------
// gi projection MFMA (unchanged from round 4)
// ---------------------------------------------------------------------------
__global__ __launch_bounds__(256, 2) void proj_mfma_k(
        const unsigned short* __restrict__ A, const unsigned short* __restrict__ wb,
        const float* __restrict__ bias, float* __restrict__ out) {
    __shared__ unsigned short At[2][128 * 64];
    __shared__ unsigned short Bt[2][128 * 64];
    const int m0 = blockIdx.y * 128;
    const int n0 = blockIdx.x * 128;
    const int tid = threadIdx.x;
    const int w = tid >> 6, l = tid & 63;
    const int wm = w >> 1, wn = w & 1;
    const int fr = l & 15, fq = l >> 4;

    f32x4 acc[4][4] = {};
    const int NT = COUT / 64;

    auto stage = [&](int buf, int k0) {
        #pragma unroll
        for (int i = 0; i < 4; ++i) {
            const int r = w * 32 + i * 8 + (l >> 3);
            const int s = l & 7, c = s ^ (r & 7);
            int mA = m0 + r; if (mA > MROWS - 1) mA = MROWS - 1;
            load_lds16(A + (size_t)mA * COUT + k0 + c * 8,
                       &At[buf][(w * 32 + i * 8) * 64]);
            load_lds16(wb + (size_t)(n0 + r) * COUT + k0 + c * 8,
                       &Bt[buf][(w * 32 + i * 8) * 64]);
        }
    };

    stage(0, 0);
    __syncthreads();
    int cur = 0;
    for (int t = 0; t < NT; ++t) {
        const int nxt = cur ^ 1;
        if (t + 1 < NT) stage(nxt, (t + 1) * 64);
        #pragma unroll
        for (int ks = 0; ks < 2; ++ks) {
            bf16x8 af[4], bfg[4];
            #pragma unroll
            for (int mf = 0; mf < 4; ++mf) {
                const int rA = wm * 64 + mf * 16 + fr;
                const int cw = ks * 4 + fq, s = cw ^ (rA & 7);
                af[mf] = *reinterpret_cast<const bf16x8*>(&At[cur][rA * 64 + s * 8]);
            }
            #pragma unroll
            for (int nf = 0; nf < 4; ++nf) {
                const int rB = wn * 64 + nf * 16 + fr;
                const int cw = ks * 4 + fq, s = cw ^ (rB & 7);
                bfg[nf] = *reinterpret_cast<const bf16x8*>(&Bt[cur][rB * 64 + s * 8]);
            }
            #pragma unroll
            for (int mf = 0; mf < 4; ++mf)
                #pragma unroll
                for (int nf = 0; nf < 4; ++nf)
                    acc[mf][nf] = __builtin_amdgcn_mfma_f32_16x16x32_bf16(
                        af[mf], bfg[nf], acc[mf][nf], 0, 0, 0);
        }
        __syncthreads();
        cur = nxt;
    }

    #pragma unroll
    for (int nf = 0; nf < 4; ++nf) {
        const int n = n0 + wn * 64 + nf * 16 + fr;
        const float bv = bias[n];
        #pragma unroll
        for (int mf = 0; mf < 4; ++mf) {
            #pragma unroll
            for (int i = 0; i < 4; ++i) {
                const int m = m0 + wm * 64 + mf * 16 + fq * 4 + i;
                if (m < MROWS)
                    out[(size_t)m * 1536 + n] = acc[mf][nf][i] + bv;
            }
        }
    }
}

// ---------------------------------------------------------------------------
// GRU scan, round 9. 8 teams x 4 slice-blocks (32 blocks x 512 thr).
// Wave-pair q (waves 2q,2q+1) OWNS k-quarter q: its 64 lanes poll exactly the
// 64 exchange words it consumes, write them to a wave-PRIVATE LDS strip
// (lgkmcnt(0) orders write->read within the wave; no barrier), then matvec.
// Gate duty = the pair with q == isl (its quarter is produced locally):
// handoff via LDS strips + 2 epoch flags, so all remote pairs start polling
// at B1+0 while gates compute in parallel. ONE __syncthreads per step.
// p_lds anti-hazard without a 2nd barrier: a pair writes p_lds for step t+1
// only after acquiring epoch t+1, which requires the own block's gates to
// have published t+1, which happens after they read p_lds for step t.
// Exchange protocol unchanged from round 3/4 (proven): relaxed agent-scope
// store of {epoch:32|2xfp16:32}, exact-epoch poll, parity double-buffer.
// ---------------------------------------------------------------------------
__global__ __launch_bounds__(512, 1) void gru_scan_k(
        const float* __restrict__ gi, const float* __restrict__ w_hh,
        const float* __restrict__ b_hh, const float* __restrict__ hidden,
        float* __restrict__ out, unsigned long long* __restrict__ h_ex) {
    const int bid = blockIdx.x;
    const int b   = bid & 7;           // team/batch
    const int isl = bid >> 3;          // slice: block owns rows isl*128..+128
    const int tid = threadIdx.x;
    const int wv  = tid >> 6;          // wave 0..7
    const int l   = tid & 63;
    const int q   = wv >> 1;           // k-quarter this wave-pair consumes
    const int g   = (wv & 1) * 64 + l; // row-in-block 0..127
    const int j   = isl * 128 + g;     // h row this thread computes (quarter q)
    const bool is_gate = (q == isl);   // pair with locally-produced quarter

    __shared__ __align__(16) __half2 strip[8][64];  // per-wave h-quarter copy
    __shared__ float p_lds[3 * 128 * 5];            // partials, stride 5
    __shared__ int lflag[2];                        // gate-wave epoch flags

    // weights: 3 gates x 128 k (quarter q) of row j -> 192 half2
    __half2 wreg[3][64];
    #pragma unroll
    for (int m = 0; m < 3; ++m) {
        const float* wp = w_hh + (size_t)(j + m * 512) * HID + q * 128;
        #pragma unroll
        for (int kk = 0; kk < 32; ++kk) {
            float4 v = reinterpret_cast<const float4*>(wp)[kk];
            wreg[m][2 * kk]     = __halves2half2(__float2half_rn(v.x), __float2half_rn(v.y));
            wreg[m][2 * kk + 1] = __halves2half2(__float2half_rn(v.z), __float2half_rn(v.w));
        }
    }

    float bhr = 0.f, bhz = 0.f, bhn = 0.f, hprev = 0.f;
    float gir = 0.f, giz = 0.f, gin = 0.f;
    if (is_gate) {
        bhr = b_hh[j]; bhz = b_hh[j + 512]; bhn = b_hh[j + 1024];
        hprev = hidden[b * HID + j];
        gir = gi[(size_t)b * 1536 + j];
        giz = gi[(size_t)b * 1536 + j + 512];
        gin = gi[(size_t)b * 1536 + j + 1024];
    }
    if (tid < 2) lflag[tid] = 0;
    // prologue: every wave fills its own strip with h_0 (epoch 0, local)
    strip[wv][l] = __halves2half2(__float2half(hidden[b * HID + q * 128 + 2 * l]),
                                  __float2half(hidden[b * HID + q * 128 + 2 * l + 1]));
    __syncthreads();

    for (int t = 0; t < TSTEPS; ++t) {
        // ---- acquire epoch t (t>0): pair-owned, no cross-wave sync ----
        if (t > 0) {
            if (!is_gate) {
                const unsigned long long* src =
                    h_ex + (size_t)((t & 1) * BATCH + b) * 256 + q * 64 + l;
                unsigned long long v;
                do {
                    v = __hip_atomic_load(src, __ATOMIC_RELAXED,
                                          __HIP_MEMORY_SCOPE_AGENT);
                } while ((unsigned)(v >> 32) != (unsigned)t);
                strip[wv][l] =
                    __builtin_bit_cast(__half2, (unsigned)(v & 0xffffffffu));
                asm volatile("s_waitcnt lgkmcnt(0)" ::: "memory");
            } else {
                volatile int* f0 = &lflag[0];
                volatile int* f1 = &lflag[1];
                while (*f0 < t || *f1 < t) {}
                asm volatile("" ::: "memory");
            }
        }
        // ---- matvec over quarter q from the wave's strip (broadcast b128) ----
        const H2x4* hv4 = reinterpret_cast<const H2x4*>(&strip[wv][0]);
        float a0 = 0, a1 = 0, a2 = 0, c0 = 0, c1 = 0, c2 = 0;
        #pragma unroll
        for (int kk = 0; kk < 16; ++kk) {
            H2x4 h4 = hv4[kk];
            a0 = dot2f(wreg[0][4 * kk + 0], h4.x, a0);
            a1 = dot2f(wreg[1][4 * kk + 0], h4.x, a1);
            a2 = dot2f(wreg[2][4 * kk + 0], h4.x, a2);
            c0 = dot2f(wreg[0][4 * kk + 1], h4.y, c0);
            c1 = dot2f(wreg[1][4 * kk + 1], h4.y, c1);
            c2 = dot2f(wreg[2][4 * kk + 1], h4.y, c2);
            a0 = dot2f(wreg[0][4 * kk + 2], h4.z, a0);
            a1 = dot2f(wreg[1][4 * kk + 2], h4.z, a1);
            a2 = dot2f(wreg[2][4 * kk + 2], h4.z, a2);
            c0 = dot2f(wreg[0][4 * kk + 3], h4.w, c0);
            c1 = dot2f(wreg[1][4 * kk + 3], h4.w, c1);
            c2 = dot2f(wreg[2][4 * kk + 3], h4.w, c2);
        }
        p_lds[(0 * 128 + g) * 5 + q] = a0 + c0;   // stride 5: conflict-free
        p_lds[(1 * 128 + g) * 5 + q] = a1 + c1;
        p_lds[(2 * 128 + g) * 5 + q] = a2 + c2;
        __syncthreads();   // B1 (the ONLY barrier per step)

        // ---- gates by pair isl; remote pairs fall through and poll t+1 ----
        if (is_gate) {
            const float* pr = &p_lds[(0 * 128 + g) * 5];
            const float* pz = &p_lds[(1 * 128 + g) * 5];
            const float* pn = &p_lds[(2 * 128 + g) * 5];
            const float ghr = (pr[0] + pr[1]) + (pr[2] + pr[3]) + bhr;
            const float ghz = (pz[0] + pz[1]) + (pz[2] + pz[3]) + bhz;
            const float ghn = (pn[0] + pn[1]) + (pn[2] + pn[3]) + bhn;
            const float rr = 1.f / (1.f + __expf(-(gir + ghr)));
            const float zz = 1.f / (1.f + __expf(-(giz + ghz)));
            const float nx = gin + rr * ghn;
            const float nn = 1.f - 2.f / (__expf(2.f * nx) + 1.f);   // tanh
            const float hnew = (1.f - zz) * nn + zz * hprev;
            hprev = hnew;
            const float hother = __shfl_xor(hnew, 1);
            if (t + 1 < TSTEPS) {
                if (!(g & 1)) {
                    const __half2 h2 = __halves2half2(__float2half(hnew),
                                                      __float2half(hother));
                    const unsigned long long v =
                        ((unsigned long long)(unsigned)(t + 1) << 32) |
                        (unsigned long long)__builtin_bit_cast(unsigned, h2);
                    // publish first (remote consumers' RT is the bottleneck)
                    __hip_atomic_store(
                        h_ex + (size_t)(((t + 1) & 1) * BATCH + b) * 256
                             + isl * 64 + (g >> 1),
                        v, __ATOMIC_RELAXED, __HIP_MEMORY_SCOPE_AGENT);
                    // local handoff for next step's own-quarter matvec
                    strip[2 * isl][g >> 1] = h2;
                    strip[2 * isl + 1][g >> 1] = h2;
                }
                asm volatile("s_waitcnt lgkmcnt(0)" ::: "memory");
                if (l == 0) lflag[wv & 1] = t + 1;   // per-gate-wave flag
                out[(size_t)(t * BATCH + b) * HID + j] = hnew;
                const float* gp = gi + (size_t)((t + 1) * BATCH + b) * 1536 + j;
                gir = gp[0]; giz = gp[512]; gin = gp[1024];
            } else {
                out[(size_t)(t * BATCH + b) * HID + j] = hnew;
            }
        }
        // no second barrier: see header comment for the anti-hazard proof
    }
    if (is_gate)
        out[(size_t)TSTEPS * BATCH * HID + b * HID + j] = hprev;
}

extern "C" void kernel_launch(void* const* d_in, const int* in_sizes, int n_in,
                              void* d_out, int out_size, void* d_ws, size_t ws_size,
                              hipStream_t stream) {
    (void)in_sizes; (void)n_in; (void)out_size; (void)ws_size;
    const float* input  = (const float*)d_in[0];
    const float* hidden = (const float*)d_in[1];
    const float* conv_w = (const float*)d_in[2];
    const float* conv_b = (const float*)d_in[3];
    const float* w_ih   = (const float*)d_in[4];
    const float* w_hh   = (const float*)d_in[5];
    const float* b_ih   = (const float*)d_in[6];
    const float* b_hh   = (const float*)d_in[7];
    float* out = (float*)d_out;

    char* ws = (char*)d_ws;
    float*          gi       = (float*)ws;                          // 50,085,888 B
    unsigned short* conv_out = (unsigned short*)(ws + 50085888);    //  8,347,648 B
    unsigned short* w_bf     = (unsigned short*)(ws + 58433536);    // 12,582,912 B
    unsigned short* wih_bf   = (unsigned short*)(ws + 71016448);    //  1,572,864 B
    unsigned long long* h_ex = (unsigned long long*)(ws + 72589312);//     32,768 B

    f2bf_k<<<2048, 256, 0, stream>>>(conv_w, w_bf, KTOT * COUT / 4);
    f2bf_k<<<768, 256, 0, stream>>>(w_ih, wih_bf, 1536 * COUT / 4);

    dim3 cgrid(4, 64);
    conv_mfma_k<<<cgrid, 256, 0, stream>>>(input, w_bf, conv_b, conv_out);

    dim3 pgrid(12, 64);
    proj_mfma_k<<<pgrid, 256, 0, stream>>>(conv_out, wih_bf, b_ih, gi);

    // reset exchange epochs each launch (replays don't re-poison d_ws)
    hipMemsetAsync(h_ex, 0, 32768, stream);

    gru_scan_k<<<32, 512, 0, stream>>>(gi, w_hh, b_hh, hidden, out, h_ex);
}